// Round 1
// 169.886 us; speedup vs baseline: 1.1385x; 1.1385x over previous
//
#include <hip/hip_runtime.h>
#include <math.h>

#define NGRAPH 256
#define HEADS  8
#define DIN    512
#define EPG    256   // edges per graph
#define NEDGE  65536

typedef short bf16x8 __attribute__((ext_vector_type(8)));
typedef float f32x4 __attribute__((ext_vector_type(4)));

__device__ __forceinline__ float softplusf(float v) {
    return (v > 20.f) ? v : log1pf(expf(v));
}
__device__ __forceinline__ unsigned short f2bf(float f) {   // RNE f32 -> bf16
    union { float f; unsigned u; } c; c.f = f;
    unsigned r = c.u + 0x7fffu + ((c.u >> 16) & 1u);
    return (unsigned short)(r >> 16);
}
__device__ __forceinline__ float bf2f(unsigned short h) {
    union { float f; unsigned u; } c; c.u = ((unsigned)h) << 16;
    return c.f;
}
// XOR-swizzled element index into a [64][64] bf16 LDS tile (16B-group granularity).
// Reads of 8 consecutive t (one group) stay contiguous/16B-aligned; row-strided
// b128 reads across 16 rows land on distinct 16B slots -> conflict-free.
__device__ __forceinline__ int swz_idx(int row, int t) {
    int g = ((t >> 3) ^ (row ^ (row >> 3))) & 7;
    return (row << 6) | (g << 3) | (t & 7);
}
// Load 8 consecutive f32, split each into bf16 hi + bf16 lo (hi = truncation,
// lo = truncation of residual). hi*hi + hi*lo + lo*hi recovers f32-level accuracy.
__device__ __forceinline__ void loadsplit(const float* p, bf16x8& hi, bf16x8& lo) {
    float4 u = *(const float4*)p;
    float4 v = *(const float4*)(p + 4);
    float vv[8] = {u.x, u.y, u.z, u.w, v.x, v.y, v.z, v.w};
    #pragma unroll
    for (int j = 0; j < 8; ++j) {
        union { float f; unsigned q; } c; c.f = vv[j];
        unsigned hb = c.q & 0xffff0000u;
        hi[j] = (short)(unsigned short)(hb >> 16);
        union { float f; unsigned q; } d; d.q = hb;
        union { float f; unsigned q; } e2; e2.f = vv[j] - d.f;
        lo[j] = (short)(unsigned short)(e2.q >> 16);
    }
}

// One block per graph (256 blocks, 512 threads = 8 waves). Wave w owns head w.
// LDS total = 8704 + 2*65536 + 14336 + 3*2048 + 256 = 160,512 B  (<= 163,840).
__global__ __launch_bounds__(512, 2) void dag_fused_kernel(
        const float* __restrict__ x,
        const float* __restrict__ Bm,
        const float* __restrict__ Cm,
        const float* __restrict__ dt,
        const float* __restrict__ dt_edge,
        const float* __restrict__ dt_bias,
        const float* __restrict__ Dp,
        const float* __restrict__ dag_masks,
        const int* __restrict__ edge_index,
        float* __restrict__ out) {
    __shared__ unsigned short CBsh[64 * 68];                   // CB[i][t] bf16, stride 68
    __shared__ __align__(16) unsigned short Xt[HEADS][4096];   // X^T[e][t] bf16, swizzled
    __shared__ __align__(16) unsigned short Wl[HEADS][4096];   // W[i][t]  bf16, swizzled
    __shared__ float Ab[HEADS][448];                           // band [i][d-1], d in 1..7
    __shared__ float dts[HEADS][64];
    __shared__ float dtt[HEADS][64];
    __shared__ float dnsh[HEADS][64];
    __shared__ float ecsh[64];                                 // head-independent

    const int b = blockIdx.x;
    const int tid = threadIdx.x;
    const int w = tid >> 6;       // wave id == head id
    const int lane = tid & 63;
    const int lm = lane & 15;
    const int quad = lane >> 4;
    const float bias = dt_bias[w];

    // ---- phase 0: zero + per-head node softplus staging ----
    {
        float2 dv = *(const float2*)(dt + ((size_t)(b * 64 + lane)) * 16 + w * 2);
        dts[w][lane] = softplusf(dv.x + bias);
        dtt[w][lane] = softplusf(dv.y + bias);
        dnsh[w][lane] = 0.f;
        #pragma unroll
        for (int s = 0; s < 7; ++s) Ab[w][lane * 7 + s] = 0.f;
        if (w == 0) ecsh[lane] = 0.f;
    }
    __syncthreads();

    // ---- phase 1: ec scatter + CB = C·B^T via split-bf16 MFMA + X^T staging ----
    if (tid < EPG) {
        int e = b * EPG + tid;
        atomicAdd(&ecsh[edge_index[NEDGE + e] & 63], dag_masks[e]);
    }
    {
        // wave w computes output tiles (mi = w>>1, ni0 = (w&1)*2 and ni0+1).
        // A-frag: C[mi*16+lm][k..k+8); B-frag: B[ni*16+lm][k..k+8)  (both row-major, direct global)
        const int mi = w >> 1;
        const int ni0 = (w & 1) * 2;
        const float* Cr = Cm + ((size_t)(b * 64 + mi * 16 + lm)) * DIN + quad * 8;
        const float* B0 = Bm + ((size_t)(b * 64 + ni0 * 16 + lm)) * DIN + quad * 8;
        const float* B1 = B0 + (size_t)16 * DIN;
        f32x4 acc0 = {0.f, 0.f, 0.f, 0.f};
        f32x4 acc1 = {0.f, 0.f, 0.f, 0.f};
        #pragma unroll 4
        for (int ks = 0; ks < 16; ++ks) {
            bf16x8 ah, al, b0h, b0l, b1h, b1l;
            loadsplit(Cr + ks * 32, ah, al);
            loadsplit(B0 + ks * 32, b0h, b0l);
            loadsplit(B1 + ks * 32, b1h, b1l);
            acc0 = __builtin_amdgcn_mfma_f32_16x16x32_bf16(ah, b0h, acc0, 0, 0, 0);
            acc0 = __builtin_amdgcn_mfma_f32_16x16x32_bf16(ah, b0l, acc0, 0, 0, 0);
            acc0 = __builtin_amdgcn_mfma_f32_16x16x32_bf16(al, b0h, acc0, 0, 0, 0);
            acc1 = __builtin_amdgcn_mfma_f32_16x16x32_bf16(ah, b1h, acc1, 0, 0, 0);
            acc1 = __builtin_amdgcn_mfma_f32_16x16x32_bf16(ah, b1l, acc1, 0, 0, 0);
            acc1 = __builtin_amdgcn_mfma_f32_16x16x32_bf16(al, b1h, acc1, 0, 0, 0);
        }
        // C/D layout: col = lane&15, row = quad*4 + r
        #pragma unroll
        for (int r = 0; r < 4; ++r) {
            int row = mi * 16 + quad * 4 + r;
            CBsh[row * 68 + ni0 * 16 + lm] = f2bf(acc0[r]);
            CBsh[row * 68 + (ni0 + 1) * 16 + lm] = f2bf(acc1[r]);
        }
    }
    {
        // stage head-w X^T tile: Xt[e][t] = x[b*64+t][w*64+e]
        const float* xg = x + (size_t)b * 64 * DIN + w * 64;
        #pragma unroll 4
        for (int r = 0; r < 16; ++r) {
            int t = r * 4 + quad;
            int e0 = lm * 4;
            float4 v = *(const float4*)(xg + (size_t)t * DIN + e0);
            Xt[w][swz_idx(e0 + 0, t)] = f2bf(v.x);
            Xt[w][swz_idx(e0 + 1, t)] = f2bf(v.y);
            Xt[w][swz_idx(e0 + 2, t)] = f2bf(v.z);
            Xt[w][swz_idx(e0 + 3, t)] = f2bf(v.w);
        }
    }
    __syncthreads();

    // ---- phase 2: per-head edge scatter (wave w -> its own band) ----
    {
        #pragma unroll
        for (int eo = 0; eo < 4; ++eo) {
            int e = b * EPG + eo * 64 + lane;
            int sl = edge_index[e] & 63;
            int dl = edge_index[NEDGE + e] & 63;
            float mk = dag_masks[e];
            float de = softplusf(dt_edge[(size_t)e * HEADS + w] + bias);
            float dsum = (dts[w][sl] + dtt[w][dl] + de) * 0.57735026918962576451f; // 1/sqrt(3)
            float dexp = expf(-dsum);
            atomicAdd(&Ab[w][dl * 7 + (dl - sl - 1)], dexp * mk);   // dl-sl in [1,7]
            atomicAdd(&dnsh[w][dl], dsum * mk);
        }
    }
    __syncthreads();

    // ---- phase 3: band normalize (lane i handles row i) ----
    {
        float eci = ecsh[lane];
        #pragma unroll
        for (int s = 0; s < 7; ++s) {
            int src = lane - 1 - s;
            if (src >= 0) {
                float den = sqrtf(eci * ecsh[src]);
                if (den < 1.f) den = 1.f;
                Ab[w][lane * 7 + s] = Ab[w][lane * 7 + s] / den;
            }
        }
    }
    __syncthreads();

    // ---- phase 4: banded forward solve — ALL 8 waves solve (one head each) ----
    // lane j = column j of M = (I-A)^-1; W[i][j] = M[i][j]*CB[i][j]*dn[i] (+D on diag)
    {
        const int j = lane;
        const float Dh = Dp[w];
        float mwin[7] = {0.f, 0.f, 0.f, 0.f, 0.f, 0.f, 0.f};
        const float* abp = &Ab[w][0];
        for (int i = 0; i < 64; ++i) {
            float mi_ = (j == i) ? 1.f : 0.f;
            #pragma unroll
            for (int s = 0; s < 7; ++s) mi_ += abp[i * 7 + s] * mwin[s];
            float wv = mi_ * bf2f(CBsh[i * 68 + j]) * dnsh[w][i];
            if (j == i) wv += Dh;
            Wl[w][swz_idx(i, j)] = f2bf(wv);   // i uniform -> conflict-free store
            #pragma unroll
            for (int s = 6; s > 0; --s) mwin[s] = mwin[s - 1];
            mwin[0] = mi_;
        }
    }
    __syncthreads();

    // ---- phase 5: y = W·X via mfma_f32_16x16x32_bf16, one wave = one head ----
    // A-frag: lane holds W[m=lane&15][k=quad*8+j]; B-frag: X[t=quad*8+j][e=lane&15] = Xt[e][t]
    {
        bf16x8 af[4][2];
        #pragma unroll
        for (int mi = 0; mi < 4; ++mi) {
            int row0 = mi * 16 + lm;
            af[mi][0] = *(const bf16x8*)(&Wl[w][swz_idx(row0, quad * 8)]);
            af[mi][1] = *(const bf16x8*)(&Wl[w][swz_idx(row0, 32 + quad * 8)]);
        }
        float* og = out + (size_t)b * 64 * DIN + w * 64;
        #pragma unroll
        for (int eb = 0; eb < 4; ++eb) {
            int er = eb * 16 + lm;
            bf16x8 b0 = *(const bf16x8*)(&Xt[w][swz_idx(er, quad * 8)]);
            bf16x8 b1 = *(const bf16x8*)(&Xt[w][swz_idx(er, 32 + quad * 8)]);
            #pragma unroll
            for (int mi = 0; mi < 4; ++mi) {
                f32x4 acc = {0.f, 0.f, 0.f, 0.f};
                acc = __builtin_amdgcn_mfma_f32_16x16x32_bf16(af[mi][0], b0, acc, 0, 0, 0);
                acc = __builtin_amdgcn_mfma_f32_16x16x32_bf16(af[mi][1], b1, acc, 0, 0, 0);
                #pragma unroll
                for (int r = 0; r < 4; ++r) {
                    int row = mi * 16 + quad * 4 + r;
                    og[(size_t)row * DIN + eb * 16 + lm] = acc[r];
                }
            }
        }
    }
}

extern "C" void kernel_launch(void* const* d_in, const int* in_sizes, int n_in,
                              void* d_out, int out_size, void* d_ws, size_t ws_size,
                              hipStream_t stream) {
    (void)in_sizes; (void)n_in; (void)out_size; (void)d_ws; (void)ws_size;
    dag_fused_kernel<<<dim3(NGRAPH), dim3(512), 0, stream>>>(
        (const float*)d_in[0],   // x
        (const float*)d_in[1],   // B
        (const float*)d_in[2],   // C
        (const float*)d_in[3],   // dt
        (const float*)d_in[4],   // dt_edge
        (const float*)d_in[5],   // dt_bias
        (const float*)d_in[6],   // D
        (const float*)d_in[7],   // dag_masks
        (const int*)d_in[8],     // edge_index
        (float*)d_out);
}